// Round 4
// baseline (1061.702 us; speedup 1.0000x reference)
//
#include <hip/hip_runtime.h>
#include <hip/hip_bf16.h>

#define N_NODES 32768
#define F_IN    32
#define HC      64
#define HEADS   4
#define NE      524288
#define NET     (NE + N_NODES)   /* 557056 = 2176*256 */
#define NG      64
#define TT      512
#define OUTF    24

// barrier that drains LDS only (no vmcnt(0) drain -> global prefetch stays in flight)
#define LDS_BARRIER() asm volatile("s_waitcnt lgkmcnt(0)\n\ts_barrier" ::: "memory")

__device__ __forceinline__ float lrelu(float x){ return x > 0.f ? x : 0.2f*x; }
__device__ __forceinline__ float eluf (float x){ return x > 0.f ? x : __expf(x)-1.f; }
__device__ __forceinline__ float sigmf(float x){ return 1.f/(1.f+__expf(-x)); }
__device__ __forceinline__ float tanhfast(float x){ return 1.f - 2.f/(__expf(2.f*x)+1.f); }

// ---------------- CSR build: incoming-edge lists per destination ----------------
__global__ __launch_bounds__(256) void k_deg(const int* __restrict__ ei,
                                             int* __restrict__ deg){
  int e = blockIdx.x*256 + threadIdx.x;   // e < NET
  int d = (e < NE) ? ei[NE+e] : (e - NE);
  atomicAdd(deg + d, 1);
}

// exclusive prefix sum of deg[32768] -> rowptr[32769]; single block of 1024
__global__ __launch_bounds__(1024) void k_scan(const int* __restrict__ deg,
                                               int* __restrict__ rowptr){
  __shared__ int ps[1024];
  const int t = threadIdx.x;
  const int base = t*32;
  int local[32]; int s = 0;
  #pragma unroll
  for(int i=0;i<32;i++){ local[i]=deg[base+i]; s+=local[i]; }
  ps[t]=s; __syncthreads();
  for(int off=1; off<1024; off<<=1){
    int v = (t>=off) ? ps[t-off] : 0;
    __syncthreads();
    ps[t]+=v;
    __syncthreads();
  }
  int run = (t==0) ? 0 : ps[t-1];
  #pragma unroll
  for(int i=0;i<32;i++){ rowptr[base+i]=run; run+=local[i]; }
  if(t==1023) rowptr[N_NODES]=run;
}

__global__ __launch_bounds__(256) void k_fill(const int* __restrict__ ei,
                                              const int* __restrict__ rowptr,
                                              int* __restrict__ cur,
                                              int* __restrict__ col){
  int e = blockIdx.x*256 + threadIdx.x;   // e < NET
  int s, d;
  if(e < NE){ s = ei[e]; d = ei[NE+e]; } else { s = e-NE; d = s; }
  int pos = atomicAdd(cur + d, 1);
  col[rowptr[d] + pos] = s;
}

// ---------------- GAT layer 1: h1 = x @ W1   [N,32]@[32,256] ----------------
__global__ __launch_bounds__(256) void k_gemm1(const float* __restrict__ x,
                                               const float* __restrict__ W1,
                                               float* __restrict__ h1){
  __shared__ __align__(16) float xs[64*32];
  __shared__ __align__(16) float ws[32*256];
  const int tid = threadIdx.x;
  const int row0 = blockIdx.x*64;
  const float4* xg = (const float4*)(x + row0*F_IN);
  float4* xs4 = (float4*)xs;
  for(int i=tid;i<512;i+=256) xs4[i]=xg[i];
  const float4* wg=(const float4*)W1; float4* ws4=(float4*)ws;
  for(int i=tid;i<2048;i+=256) ws4[i]=wg[i];
  __syncthreads();
  float wc[32];
  #pragma unroll
  for(int k=0;k<32;k++) wc[k]=ws[k*256+tid];
  for(int r=0;r<64;r++){
    const float4* xr=(const float4*)(xs + r*32);
    float acc=0.f;
    #pragma unroll
    for(int k4=0;k4<8;k4++){
      float4 v=xr[k4];
      acc += v.x*wc[4*k4]+v.y*wc[4*k4+1]+v.z*wc[4*k4+2]+v.w*wc[4*k4+3];
    }
    h1[(row0+r)*256+tid]=acc;
  }
}

__global__ __launch_bounds__(256) void k_alpha1(const float* __restrict__ h1,
                                                const float* __restrict__ a_src,
                                                const float* __restrict__ a_dst,
                                                float* __restrict__ as1,
                                                float* __restrict__ ad1){
  int t = blockIdx.x*256 + threadIdx.x;   // t < N*4
  int n = t>>2, h = t&3;
  const float4* hp=(const float4*)(h1 + n*256 + h*64);
  const float4* ap=(const float4*)(a_src + h*64);
  const float4* dp=(const float4*)(a_dst + h*64);
  float sa=0.f, sd=0.f;
  #pragma unroll
  for(int i=0;i<16;i++){
    float4 v=hp[i], a=ap[i], d=dp[i];
    sa += v.x*a.x+v.y*a.y+v.z*a.z+v.w*a.w;
    sd += v.x*d.x+v.y*d.y+v.z*d.z+v.w*d.w;
  }
  as1[t]=sa; ad1[t]=sd;
}

// fused gather: softmax (no max-subtract; logits O(5)) + aggregate + bias + ELU.
// one wave per node; lane covers one float4 of 256 output channels; head = lane>>4.
__global__ __launch_bounds__(256) void k_gat1(const int* __restrict__ rowptr,
                                              const int* __restrict__ col,
                                              const float* __restrict__ as1,
                                              const float* __restrict__ ad1,
                                              const float* __restrict__ h1,
                                              const float* __restrict__ b1,
                                              float* __restrict__ out1){
  const int node = blockIdx.x*4 + (threadIdx.x>>6);
  const int lane = threadIdx.x & 63;
  const int h    = lane>>4;
  const int beg = rowptr[node], end = rowptr[node+1];
  const float ad = ad1[node*4+h];
  float4 acc = make_float4(0.f,0.f,0.f,0.f);
  float s = 0.f;
  int j = beg;
  for(; j+1 < end; j += 2){
    int s0 = col[j], s1 = col[j+1];
    float w0 = __expf(lrelu(as1[s0*4+h] + ad));
    float w1 = __expf(lrelu(as1[s1*4+h] + ad));
    float4 v0 = *(const float4*)(h1 + s0*256 + lane*4);
    float4 v1 = *(const float4*)(h1 + s1*256 + lane*4);
    acc.x += w0*v0.x + w1*v1.x;
    acc.y += w0*v0.y + w1*v1.y;
    acc.z += w0*v0.z + w1*v1.z;
    acc.w += w0*v0.w + w1*v1.w;
    s += w0 + w1;
  }
  if(j < end){
    int s0 = col[j];
    float w0 = __expf(lrelu(as1[s0*4+h] + ad));
    float4 v0 = *(const float4*)(h1 + s0*256 + lane*4);
    acc.x += w0*v0.x; acc.y += w0*v0.y; acc.z += w0*v0.z; acc.w += w0*v0.w;
    s += w0;
  }
  const float inv = 1.f/(s + 1e-16f);
  float4 bb = ((const float4*)b1)[lane];
  float4 o;
  o.x = eluf(acc.x*inv + bb.x);
  o.y = eluf(acc.y*inv + bb.y);
  o.z = eluf(acc.z*inv + bb.z);
  o.w = eluf(acc.w*inv + bb.w);
  ((float4*)(out1 + node*256))[lane] = o;
}

// ---------------- GAT layer 2: h2 = out1 @ W2   [N,256]@[256,64] ----------------
__global__ __launch_bounds__(256) void k_gemm2(const float* __restrict__ in,
                                               const float* __restrict__ W2,
                                               float* __restrict__ h2){
  __shared__ __align__(16) float xs[64*256];
  const int tid=threadIdx.x;
  const int row0=blockIdx.x*64;
  const float4* xg=(const float4*)(in + row0*256);
  float4* xs4=(float4*)xs;
  for(int i=tid;i<4096;i+=256) xs4[i]=xg[i];
  __syncthreads();
  const int c0=(tid&15)*4;
  const int r0=(tid>>4)*4;
  float acc[4][4]={};
  for(int k=0;k<256;k+=4){
    float wv[4][4];
    #pragma unroll
    for(int i=0;i<4;i++){
      float4 w=*(const float4*)(W2+(k+i)*64+c0);
      wv[i][0]=w.x; wv[i][1]=w.y; wv[i][2]=w.z; wv[i][3]=w.w;
    }
    #pragma unroll
    for(int i=0;i<4;i++){
      float4 xv=*(const float4*)(xs+(r0+i)*256+k);
      #pragma unroll
      for(int j=0;j<4;j++)
        acc[i][j]+=xv.x*wv[0][j]+xv.y*wv[1][j]+xv.z*wv[2][j]+xv.w*wv[3][j];
    }
  }
  #pragma unroll
  for(int i=0;i<4;i++)
    *(float4*)(h2+(row0+r0+i)*64+c0)=make_float4(acc[i][0],acc[i][1],acc[i][2],acc[i][3]);
}

__global__ __launch_bounds__(256) void k_alpha2(const float* __restrict__ h2,
                                                const float* __restrict__ a_src,
                                                const float* __restrict__ a_dst,
                                                float* __restrict__ as2,
                                                float* __restrict__ ad2){
  int n = blockIdx.x*256 + threadIdx.x;   // n < N
  const float4* hp=(const float4*)(h2+n*64);
  float sa=0.f, sd=0.f;
  #pragma unroll
  for(int i=0;i<16;i++){
    float4 v=hp[i];
    float4 a=((const float4*)a_src)[i];
    float4 d=((const float4*)a_dst)[i];
    sa+=v.x*a.x+v.y*a.y+v.z*a.z+v.w*a.w;
    sd+=v.x*d.x+v.y*d.y+v.z*d.z+v.w*d.w;
  }
  as2[n]=sa; ad2[n]=sd;
}

// fused gather layer 2: one wave per node, lane = channel (64 channels)
__global__ __launch_bounds__(256) void k_gat2(const int* __restrict__ rowptr,
                                              const int* __restrict__ col,
                                              const float* __restrict__ as2,
                                              const float* __restrict__ ad2,
                                              const float* __restrict__ h2,
                                              const float* __restrict__ b2,
                                              float* __restrict__ out2){
  const int node = blockIdx.x*4 + (threadIdx.x>>6);
  const int lane = threadIdx.x & 63;
  const int beg = rowptr[node], end = rowptr[node+1];
  const float ad = ad2[node];
  float acc = 0.f, s = 0.f;
  int j = beg;
  for(; j+1 < end; j += 2){
    int s0 = col[j], s1 = col[j+1];
    float w0 = __expf(lrelu(as2[s0] + ad));
    float w1 = __expf(lrelu(as2[s1] + ad));
    acc += w0*h2[s0*64+lane] + w1*h2[s1*64+lane];
    s += w0 + w1;
  }
  if(j < end){
    int s0 = col[j];
    float w0 = __expf(lrelu(as2[s0] + ad));
    acc += w0*h2[s0*64+lane];
    s += w0;
  }
  const float inv = 1.f/(s + 1e-16f);
  out2[node*64+lane] = eluf(acc*inv + b2[lane]);
}

// ---------------- GRU: gi1 = in @ Wih0^T + bih0   [N,64]@[64,192] ----------------
__global__ __launch_bounds__(256) void k_gemm_gi(const float* __restrict__ in,
                                                 const float* __restrict__ Wih,
                                                 const float* __restrict__ bih,
                                                 float* __restrict__ gi){
  __shared__ __align__(16) float xs[64*64];
  __shared__ float wT[64*192];
  const int tid=threadIdx.x;
  const int row0=blockIdx.x*64;
  const float4* xg=(const float4*)(in+row0*64);
  float4* xs4=(float4*)xs;
  for(int i=tid;i<1024;i+=256) xs4[i]=xg[i];
  for(int i=tid;i<12288;i+=256){ wT[(i&63)*192+(i>>6)] = Wih[i]; }
  __syncthreads();
  if(tid<192){
    float wr[64];
    #pragma unroll
    for(int k=0;k<64;k++) wr[k]=wT[k*192+tid];
    const float bj=bih[tid];
    for(int r=0;r<64;r++){
      float acc=bj;
      const float4* xr=(const float4*)(xs+r*64);
      #pragma unroll
      for(int k4=0;k4<16;k4++){
        float4 v=xr[k4];
        acc+=v.x*wr[4*k4]+v.y*wr[4*k4+1]+v.z*wr[4*k4+2]+v.w*wr[4*k4+3];
      }
      gi[(row0+r)*192+tid]=acc;
    }
  }
}

// Fused 2-layer GRU, software-pipelined one step skewed.
// 576 threads: crewA tid[0,192)   : gh1 = bhh0 + Whh0 . h1      (layer-1 recurrent)
//              crewB tid[192,384) : gi2 = bih1 + Wih1 . h1      (layer-2 input)
//              crewC tid[384,576) : gh2 = bhh1 + Whh1 . h2      (layer-2 recurrent)
// Iter i: L1 computes step i (i<512), L2 computes step i-1 (i>=1). 513 iters.
// In-loop barriers are LDS-only (no vmcnt drain) so the 2-deep gi1 prefetch
// stays in flight across barriers — its wait lands at the use, 2 iters later.
__global__ __launch_bounds__(576) void k_gru2(const float* __restrict__ gi1,
                                              const float* __restrict__ Whh0,
                                              const float* __restrict__ bhh0,
                                              const float* __restrict__ Wih1,
                                              const float* __restrict__ bih1,
                                              const float* __restrict__ Whh1,
                                              const float* __restrict__ bhh1,
                                              const float* __restrict__ Wl,
                                              const float* __restrict__ bl,
                                              float* __restrict__ fout){
  __shared__ __align__(16) float h1s[64];
  __shared__ __align__(16) float h2s[64];
  __shared__ float gis1[192];
  __shared__ float gh1s[192];
  __shared__ float gi2s[192];
  __shared__ float gh2s[192];
  const int tid = threadIdx.x;
  const int b   = blockIdx.x;

  // per-thread weight row into registers (one-time)
  const float* Wsel; float bsel; int g;
  if(tid < 192){ g = tid;     Wsel = Whh0; bsel = bhh0[g]; }
  else if(tid < 384){ g = tid-192; Wsel = Wih1; bsel = bih1[g]; }
  else{ g = tid-384; Wsel = Whh1; bsel = bhh1[g]; }
  float wr[64];
  {
    const float4* wp = (const float4*)(Wsel + g*64);
    #pragma unroll
    for(int k4=0;k4<16;k4++){
      float4 w = wp[k4];
      wr[4*k4]=w.x; wr[4*k4+1]=w.y; wr[4*k4+2]=w.z; wr[4*k4+3]=w.w;
    }
  }
  if(tid < 64){ h1s[tid]=0.f; h2s[tid]=0.f; }
  __syncthreads();

  const float* gib = gi1 + (size_t)b*TT*192;
  float giv0 = (tid < 192) ? gib[tid]       : 0.f;   // gi1 for t=0
  float giv1 = (tid < 192) ? gib[192 + tid] : 0.f;   // gi1 for t=1

  for(int i=0;i<=TT;i++){
    // ---- phase A: three matvecs + gi1 staging/prefetch ----
    if(tid < 192){
      if(i < TT){
        gis1[tid] = giv0;
        giv0 = giv1;
        int nx = i+2;
        if(nx < TT) giv1 = gib[nx*192 + tid];   // 2-deep prefetch, stays in flight
        float a0=0.f,a1=0.f,a2=0.f,a3=0.f;
        #pragma unroll
        for(int k4=0;k4<16;k4++){
          float4 h4 = *(const float4*)(h1s + 4*k4);  // LDS broadcast
          a0 += h4.x*wr[4*k4];   a1 += h4.y*wr[4*k4+1];
          a2 += h4.z*wr[4*k4+2]; a3 += h4.w*wr[4*k4+3];
        }
        gh1s[tid] = bsel + ((a0+a1)+(a2+a3));
      }
    } else if(tid < 384){
      if(i >= 1){
        float a0=0.f,a1=0.f,a2=0.f,a3=0.f;
        #pragma unroll
        for(int k4=0;k4<16;k4++){
          float4 h4 = *(const float4*)(h1s + 4*k4);
          a0 += h4.x*wr[4*k4];   a1 += h4.y*wr[4*k4+1];
          a2 += h4.z*wr[4*k4+2]; a3 += h4.w*wr[4*k4+3];
        }
        gi2s[g] = bsel + ((a0+a1)+(a2+a3));
      }
    } else {
      if(i >= 1){
        float a0=0.f,a1=0.f,a2=0.f,a3=0.f;
        #pragma unroll
        for(int k4=0;k4<16;k4++){
          float4 h4 = *(const float4*)(h2s + 4*k4);
          a0 += h4.x*wr[4*k4];   a1 += h4.y*wr[4*k4+1];
          a2 += h4.z*wr[4*k4+2]; a3 += h4.w*wr[4*k4+3];
        }
        gh2s[g] = bsel + ((a0+a1)+(a2+a3));
      }
    }
    LDS_BARRIER();
    // ---- phase B: gate updates ----
    if(tid < 64){
      if(i < TT){
        float r = sigmf(gis1[tid]     + gh1s[tid]);
        float z = sigmf(gis1[64+tid]  + gh1s[64+tid]);
        float n = tanhfast(gis1[128+tid] + r*gh1s[128+tid]);
        h1s[tid] = (1.f-z)*n + z*h1s[tid];
      }
    } else if(tid < 128){
      if(i >= 1){
        int c = tid-64;
        float r = sigmf(gi2s[c]     + gh2s[c]);
        float z = sigmf(gi2s[64+c]  + gh2s[64+c]);
        float n = tanhfast(gi2s[128+c] + r*gh2s[128+c]);
        h2s[c] = (1.f-z)*n + z*h2s[c];
      }
    }
    LDS_BARRIER();
  }

  if(tid < 24){
    float acc = bl[tid];
    const float4* wl4 = (const float4*)(Wl + tid*64);
    #pragma unroll
    for(int k4=0;k4<16;k4++){
      float4 h4 = *(const float4*)(h2s + 4*k4);
      float4 w4 = wl4[k4];
      acc += h4.x*w4.x + h4.y*w4.y + h4.z*w4.z + h4.w*w4.w;
    }
    fout[b*24+tid] = acc;
  }
}

extern "C" void kernel_launch(void* const* d_in, const int* in_sizes, int n_in,
                              void* d_out, int out_size, void* d_ws, size_t ws_size,
                              hipStream_t stream){
  const float* x     =(const float*)d_in[0];
  const int*   ei    =(const int*  )d_in[1];
  const float* W1    =(const float*)d_in[3];
  const float* a_src1=(const float*)d_in[4];
  const float* a_dst1=(const float*)d_in[5];
  const float* b1    =(const float*)d_in[6];
  const float* W2    =(const float*)d_in[7];
  const float* a_src2=(const float*)d_in[8];
  const float* a_dst2=(const float*)d_in[9];
  const float* b2    =(const float*)d_in[10];
  const float* Wih0  =(const float*)d_in[11];
  const float* Whh0  =(const float*)d_in[12];
  const float* bih0  =(const float*)d_in[13];
  const float* bhh0  =(const float*)d_in[14];
  const float* Wih1  =(const float*)d_in[15];
  const float* Whh1  =(const float*)d_in[16];
  const float* bih1  =(const float*)d_in[17];
  const float* bhh1  =(const float*)d_in[18];
  const float* Wl    =(const float*)d_in[19];
  const float* bl    =(const float*)d_in[20];

  float* ws   = (float*)d_ws;
  float* h1   = ws;                  // 8388608 (dead after k_gat1)
  float* gi   = ws;                  // alias: written by k_gemm_gi after h1 is dead
  float* out1 = ws + 8388608;        // 8388608
  float* out2 = out1;                // alias (out1 dead after k_gemm2)
  float* h2   = ws + 16777216;       // 2097152
  float* as1  = ws + 18874368;       // 131072
  float* ad1  = as1 + 131072;        // 131072
  float* as2  = ad1 + 131072;        // 32768
  float* ad2  = as2 + 32768;         // 32768
  int* rowptr = (int*)(ad2 + 32768); // 32769 (padded to 32800)
  int* deg    = rowptr + 32800;      // 32768
  int* cur    = deg + 32768;         // 32768 (contiguous with deg: one memset)
  int* col    = cur + 32768;         // 557056
  float* fo   = (float*)d_out;

  hipMemsetAsync(deg, 0, 2*32768*sizeof(int), stream);  // deg + cur

  k_deg  <<<2176,256,0,stream>>>(ei,deg);
  k_scan <<<1  ,1024,0,stream>>>(deg,rowptr);
  k_fill <<<2176,256,0,stream>>>(ei,rowptr,cur,col);

  k_gemm1 <<<512 ,256,0,stream>>>(x,W1,h1);
  k_alpha1<<<512 ,256,0,stream>>>(h1,a_src1,a_dst1,as1,ad1);
  k_gat1  <<<8192,256,0,stream>>>(rowptr,col,as1,ad1,h1,b1,out1);
  k_gemm2 <<<512 ,256,0,stream>>>(out1,W2,h2);
  k_alpha2<<<128 ,256,0,stream>>>(h2,a_src2,a_dst2,as2,ad2);
  k_gat2  <<<8192,256,0,stream>>>(rowptr,col,as2,ad2,h2,b2,out2);
  k_gemm_gi<<<512,256,0,stream>>>(out2,Wih0,bih0,gi);
  k_gru2  <<<64 ,576,0,stream>>>(gi,Whh0,bhh0,Wih1,bih1,Whh1,bhh1,Wl,bl,fo);
  (void)in_sizes; (void)n_in; (void)out_size; (void)ws_size;
}

// Round 5
// 850.455 us; speedup vs baseline: 1.2484x; 1.2484x over previous
//
#include <hip/hip_runtime.h>
#include <hip/hip_bf16.h>

#define N_NODES 32768
#define F_IN    32
#define HC      64
#define HEADS   4
#define NE      524288
#define NET     (NE + N_NODES)   /* 557056 = 2176*256 */
#define NG      64
#define TT      512
#define OUTF    24

__device__ __forceinline__ float lrelu(float x){ return x > 0.f ? x : 0.2f*x; }
__device__ __forceinline__ float eluf (float x){ return x > 0.f ? x : __expf(x)-1.f; }
__device__ __forceinline__ float sigmf(float x){ return 1.f/(1.f+__expf(-x)); }
__device__ __forceinline__ float tanhfast(float x){ return 1.f - 2.f/(__expf(2.f*x)+1.f); }
__device__ __forceinline__ float bcast(float v, int k){
  return __int_as_float(__builtin_amdgcn_readlane(__float_as_int(v), k));
}

// ---------------- CSR build: incoming-edge lists per destination ----------------
__global__ __launch_bounds__(256) void k_deg(const int* __restrict__ ei,
                                             int* __restrict__ deg){
  int e = blockIdx.x*256 + threadIdx.x;   // e < NET
  int d = (e < NE) ? ei[NE+e] : (e - NE);
  atomicAdd(deg + d, 1);
}

// exclusive prefix sum of deg[32768] -> rowptr[32769]; single block of 1024
__global__ __launch_bounds__(1024) void k_scan(const int* __restrict__ deg,
                                               int* __restrict__ rowptr){
  __shared__ int ps[1024];
  const int t = threadIdx.x;
  const int base = t*32;
  int local[32]; int s = 0;
  #pragma unroll
  for(int i=0;i<32;i++){ local[i]=deg[base+i]; s+=local[i]; }
  ps[t]=s; __syncthreads();
  for(int off=1; off<1024; off<<=1){
    int v = (t>=off) ? ps[t-off] : 0;
    __syncthreads();
    ps[t]+=v;
    __syncthreads();
  }
  int run = (t==0) ? 0 : ps[t-1];
  #pragma unroll
  for(int i=0;i<32;i++){ rowptr[base+i]=run; run+=local[i]; }
  if(t==1023) rowptr[N_NODES]=run;
}

__global__ __launch_bounds__(256) void k_fill(const int* __restrict__ ei,
                                              const int* __restrict__ rowptr,
                                              int* __restrict__ cur,
                                              int* __restrict__ col){
  int e = blockIdx.x*256 + threadIdx.x;   // e < NET
  int s, d;
  if(e < NE){ s = ei[e]; d = ei[NE+e]; } else { s = e-NE; d = s; }
  int pos = atomicAdd(cur + d, 1);
  col[rowptr[d] + pos] = s;
}

// ---------------- GAT layer 1: h1 = x @ W1   [N,32]@[32,256] ----------------
__global__ __launch_bounds__(256) void k_gemm1(const float* __restrict__ x,
                                               const float* __restrict__ W1,
                                               float* __restrict__ h1){
  __shared__ __align__(16) float xs[64*32];
  __shared__ __align__(16) float ws[32*256];
  const int tid = threadIdx.x;
  const int row0 = blockIdx.x*64;
  const float4* xg = (const float4*)(x + row0*F_IN);
  float4* xs4 = (float4*)xs;
  for(int i=tid;i<512;i+=256) xs4[i]=xg[i];
  const float4* wg=(const float4*)W1; float4* ws4=(float4*)ws;
  for(int i=tid;i<2048;i+=256) ws4[i]=wg[i];
  __syncthreads();
  float wc[32];
  #pragma unroll
  for(int k=0;k<32;k++) wc[k]=ws[k*256+tid];
  for(int r=0;r<64;r++){
    const float4* xr=(const float4*)(xs + r*32);
    float acc=0.f;
    #pragma unroll
    for(int k4=0;k4<8;k4++){
      float4 v=xr[k4];
      acc += v.x*wc[4*k4]+v.y*wc[4*k4+1]+v.z*wc[4*k4+2]+v.w*wc[4*k4+3];
    }
    h1[(row0+r)*256+tid]=acc;
  }
}

__global__ __launch_bounds__(256) void k_alpha1(const float* __restrict__ h1,
                                                const float* __restrict__ a_src,
                                                const float* __restrict__ a_dst,
                                                float* __restrict__ as1,
                                                float* __restrict__ ad1){
  int t = blockIdx.x*256 + threadIdx.x;   // t < N*4
  int n = t>>2, h = t&3;
  const float4* hp=(const float4*)(h1 + n*256 + h*64);
  const float4* ap=(const float4*)(a_src + h*64);
  const float4* dp=(const float4*)(a_dst + h*64);
  float sa=0.f, sd=0.f;
  #pragma unroll
  for(int i=0;i<16;i++){
    float4 v=hp[i], a=ap[i], d=dp[i];
    sa += v.x*a.x+v.y*a.y+v.z*a.z+v.w*a.w;
    sd += v.x*d.x+v.y*d.y+v.z*d.z+v.w*d.w;
  }
  as1[t]=sa; ad1[t]=sd;
}

// fused gather: softmax (no max-subtract; logits O(5)) + aggregate + bias + ELU.
// one wave per node; lane covers one float4 of 256 output channels; head = lane>>4.
__global__ __launch_bounds__(256) void k_gat1(const int* __restrict__ rowptr,
                                              const int* __restrict__ col,
                                              const float* __restrict__ as1,
                                              const float* __restrict__ ad1,
                                              const float* __restrict__ h1,
                                              const float* __restrict__ b1,
                                              float* __restrict__ out1){
  const int node = blockIdx.x*4 + (threadIdx.x>>6);
  const int lane = threadIdx.x & 63;
  const int h    = lane>>4;
  const int beg = rowptr[node], end = rowptr[node+1];
  const float ad = ad1[node*4+h];
  float4 acc = make_float4(0.f,0.f,0.f,0.f);
  float s = 0.f;
  int j = beg;
  for(; j+1 < end; j += 2){
    int s0 = col[j], s1 = col[j+1];
    float w0 = __expf(lrelu(as1[s0*4+h] + ad));
    float w1 = __expf(lrelu(as1[s1*4+h] + ad));
    float4 v0 = *(const float4*)(h1 + s0*256 + lane*4);
    float4 v1 = *(const float4*)(h1 + s1*256 + lane*4);
    acc.x += w0*v0.x + w1*v1.x;
    acc.y += w0*v0.y + w1*v1.y;
    acc.z += w0*v0.z + w1*v1.z;
    acc.w += w0*v0.w + w1*v1.w;
    s += w0 + w1;
  }
  if(j < end){
    int s0 = col[j];
    float w0 = __expf(lrelu(as1[s0*4+h] + ad));
    float4 v0 = *(const float4*)(h1 + s0*256 + lane*4);
    acc.x += w0*v0.x; acc.y += w0*v0.y; acc.z += w0*v0.z; acc.w += w0*v0.w;
    s += w0;
  }
  const float inv = 1.f/(s + 1e-16f);
  float4 bb = ((const float4*)b1)[lane];
  float4 o;
  o.x = eluf(acc.x*inv + bb.x);
  o.y = eluf(acc.y*inv + bb.y);
  o.z = eluf(acc.z*inv + bb.z);
  o.w = eluf(acc.w*inv + bb.w);
  ((float4*)(out1 + node*256))[lane] = o;
}

// ---------------- GAT layer 2: h2 = out1 @ W2   [N,256]@[256,64] ----------------
__global__ __launch_bounds__(256) void k_gemm2(const float* __restrict__ in,
                                               const float* __restrict__ W2,
                                               float* __restrict__ h2){
  __shared__ __align__(16) float xs[64*256];
  const int tid=threadIdx.x;
  const int row0=blockIdx.x*64;
  const float4* xg=(const float4*)(in + row0*256);
  float4* xs4=(float4*)xs;
  for(int i=tid;i<4096;i+=256) xs4[i]=xg[i];
  __syncthreads();
  const int c0=(tid&15)*4;
  const int r0=(tid>>4)*4;
  float acc[4][4]={};
  for(int k=0;k<256;k+=4){
    float wv[4][4];
    #pragma unroll
    for(int i=0;i<4;i++){
      float4 w=*(const float4*)(W2+(k+i)*64+c0);
      wv[i][0]=w.x; wv[i][1]=w.y; wv[i][2]=w.z; wv[i][3]=w.w;
    }
    #pragma unroll
    for(int i=0;i<4;i++){
      float4 xv=*(const float4*)(xs+(r0+i)*256+k);
      #pragma unroll
      for(int j=0;j<4;j++)
        acc[i][j]+=xv.x*wv[0][j]+xv.y*wv[1][j]+xv.z*wv[2][j]+xv.w*wv[3][j];
    }
  }
  #pragma unroll
  for(int i=0;i<4;i++)
    *(float4*)(h2+(row0+r0+i)*64+c0)=make_float4(acc[i][0],acc[i][1],acc[i][2],acc[i][3]);
}

__global__ __launch_bounds__(256) void k_alpha2(const float* __restrict__ h2,
                                                const float* __restrict__ a_src,
                                                const float* __restrict__ a_dst,
                                                float* __restrict__ as2,
                                                float* __restrict__ ad2){
  int n = blockIdx.x*256 + threadIdx.x;   // n < N
  const float4* hp=(const float4*)(h2+n*64);
  float sa=0.f, sd=0.f;
  #pragma unroll
  for(int i=0;i<16;i++){
    float4 v=hp[i];
    float4 a=((const float4*)a_src)[i];
    float4 d=((const float4*)a_dst)[i];
    sa+=v.x*a.x+v.y*a.y+v.z*a.z+v.w*a.w;
    sd+=v.x*d.x+v.y*d.y+v.z*d.z+v.w*d.w;
  }
  as2[n]=sa; ad2[n]=sd;
}

// fused gather layer 2: one wave per node, lane = channel (64 channels)
__global__ __launch_bounds__(256) void k_gat2(const int* __restrict__ rowptr,
                                              const int* __restrict__ col,
                                              const float* __restrict__ as2,
                                              const float* __restrict__ ad2,
                                              const float* __restrict__ h2,
                                              const float* __restrict__ b2,
                                              float* __restrict__ out2){
  const int node = blockIdx.x*4 + (threadIdx.x>>6);
  const int lane = threadIdx.x & 63;
  const int beg = rowptr[node], end = rowptr[node+1];
  const float ad = ad2[node];
  float acc = 0.f, s = 0.f;
  int j = beg;
  for(; j+1 < end; j += 2){
    int s0 = col[j], s1 = col[j+1];
    float w0 = __expf(lrelu(as2[s0] + ad));
    float w1 = __expf(lrelu(as2[s1] + ad));
    acc += w0*h2[s0*64+lane] + w1*h2[s1*64+lane];
    s += w0 + w1;
  }
  if(j < end){
    int s0 = col[j];
    float w0 = __expf(lrelu(as2[s0] + ad));
    acc += w0*h2[s0*64+lane];
    s += w0;
  }
  const float inv = 1.f/(s + 1e-16f);
  out2[node*64+lane] = eluf(acc*inv + b2[lane]);
}

// ---------------- GRU: gi1 = in @ Wih0^T + bih0   [N,64]@[64,192] ----------------
__global__ __launch_bounds__(256) void k_gemm_gi(const float* __restrict__ in,
                                                 const float* __restrict__ Wih,
                                                 const float* __restrict__ bih,
                                                 float* __restrict__ gi){
  __shared__ __align__(16) float xs[64*64];
  __shared__ float wT[64*192];
  const int tid=threadIdx.x;
  const int row0=blockIdx.x*64;
  const float4* xg=(const float4*)(in+row0*64);
  float4* xs4=(float4*)xs;
  for(int i=tid;i<1024;i+=256) xs4[i]=xg[i];
  for(int i=tid;i<12288;i+=256){ wT[(i&63)*192+(i>>6)] = Wih[i]; }
  __syncthreads();
  if(tid<192){
    float wr[64];
    #pragma unroll
    for(int k=0;k<64;k++) wr[k]=wT[k*192+tid];
    const float bj=bih[tid];
    for(int r=0;r<64;r++){
      float acc=bj;
      const float4* xr=(const float4*)(xs+r*64);
      #pragma unroll
      for(int k4=0;k4<16;k4++){
        float4 v=xr[k4];
        acc+=v.x*wr[4*k4]+v.y*wr[4*k4+1]+v.z*wr[4*k4+2]+v.w*wr[4*k4+3];
      }
      gi[(row0+r)*192+tid]=acc;
    }
  }
}

// Fused 2-layer GRU: lane-distributed state, v_readlane broadcasts, 1 barrier/step.
// 4 waves/block, 1 block/graph:
//  wave0: layer-1 recurrence. lane l holds h1[l] + Whh0 rows {l,64+l,128+l} (regs).
//         Per step: 64 readlane + 192 FMA + gates. Zero LDS on the h1->h1 chain.
//  wave2: gi2 = bih1 + Wih1 . h1  (h1 from LDS slot, 1 step behind wave0)
//  wave1: layer-2 recurrence (h2 in regs), consumes gi2 from LDS, 2 steps behind.
//  wave3: gi1 loader: global -> 4-slot LDS ring, 2 steps ahead. Its vmcnt drain
//         at the barrier overlaps the other waves' ~500-cycle compute.
__global__ __launch_bounds__(256,1) void k_gru_pipe(const float* __restrict__ gi1,
                                                    const float* __restrict__ Whh0,
                                                    const float* __restrict__ bhh0,
                                                    const float* __restrict__ Wih1,
                                                    const float* __restrict__ bih1,
                                                    const float* __restrict__ Whh1,
                                                    const float* __restrict__ bhh1,
                                                    const float* __restrict__ Wl,
                                                    const float* __restrict__ bl,
                                                    float* __restrict__ fout){
  __shared__ float h1s[2][64];     // h1 history (parity slots)
  __shared__ float gi2s[2][192];   // layer-2 input gates (parity slots)
  __shared__ float gi1b[4][192];   // gi1 ring, 2-deep prefetch
  __shared__ float h2fin[64];
  const int tid  = threadIdx.x;
  const int w    = tid >> 6;
  const int lane = tid & 63;
  const int b    = blockIdx.x;
  const float* gib = gi1 + (size_t)b*TT*192;

  // weight rows {lane, 64+lane, 128+lane} into registers (one-time)
  float w0[64], w1[64], w2[64];
  float b0=0.f, b1=0.f, b2=0.f;
  {
    const float* Wsel = (w==0)?Whh0 : (w==1)?Whh1 : Wih1;
    const float* bsel = (w==0)?bhh0 : (w==1)?bhh1 : bih1;
    if(w < 3){
      const float4* r0 = (const float4*)(Wsel + lane*64);
      const float4* r1 = (const float4*)(Wsel + (64+lane)*64);
      const float4* r2 = (const float4*)(Wsel + (128+lane)*64);
      #pragma unroll
      for(int k4=0;k4<16;k4++){
        float4 a=r0[k4], c=r1[k4], d=r2[k4];
        w0[4*k4]=a.x; w0[4*k4+1]=a.y; w0[4*k4+2]=a.z; w0[4*k4+3]=a.w;
        w1[4*k4]=c.x; w1[4*k4+1]=c.y; w1[4*k4+2]=c.z; w1[4*k4+3]=c.w;
        w2[4*k4]=d.x; w2[4*k4+1]=d.y; w2[4*k4+2]=d.z; w2[4*k4+3]=d.w;
      }
      b0=bsel[lane]; b1=bsel[64+lane]; b2=bsel[128+lane];
    } else {
      // prefill gi1 ring with steps 0,1
      #pragma unroll
      for(int s=0;s<2;s++){
        float v0=gib[s*192+lane], v1=gib[s*192+64+lane], v2=gib[s*192+128+lane];
        gi1b[s][lane]=v0; gi1b[s][64+lane]=v1; gi1b[s][128+lane]=v2;
      }
    }
  }
  float h1r = 0.f, h2r = 0.f;
  __syncthreads();

  for(int i=0;i<TT+2;i++){
    if(w == 0){
      if(i < TT){
        float gr = gi1b[i&3][lane];
        float gz = gi1b[i&3][64+lane];
        float gn = gi1b[i&3][128+lane];
        float a0=b0, a1=b1, a2=b2;
        #pragma unroll
        for(int k=0;k<64;k++){
          float hk = bcast(h1r, k);
          a0 = fmaf(hk, w0[k], a0);
          a1 = fmaf(hk, w1[k], a1);
          a2 = fmaf(hk, w2[k], a2);
        }
        float r = sigmf(gr + a0);
        float z = sigmf(gz + a1);
        float n = tanhfast(gn + r*a2);
        h1r = (1.f-z)*n + z*h1r;
        h1s[i&1][lane] = h1r;
      }
    } else if(w == 2){
      if(i >= 1 && i <= TT){
        float h1v = h1s[(i-1)&1][lane];
        float a0=b0, a1=b1, a2=b2;
        #pragma unroll
        for(int k=0;k<64;k++){
          float hk = bcast(h1v, k);
          a0 = fmaf(hk, w0[k], a0);   // note: w0/w1/w2 are Wih1 rows here
          a1 = fmaf(hk, w1[k], a1);
          a2 = fmaf(hk, w2[k], a2);
        }
        gi2s[(i-1)&1][lane]     = a0;
        gi2s[(i-1)&1][64+lane]  = a1;
        gi2s[(i-1)&1][128+lane] = a2;
      }
    } else if(w == 1){
      if(i >= 2){
        float gr = gi2s[i&1][lane];      // (i-2)&1 == i&1
        float gz = gi2s[i&1][64+lane];
        float gn = gi2s[i&1][128+lane];
        float a0=b0, a1=b1, a2=b2;
        #pragma unroll
        for(int k=0;k<64;k++){
          float hk = bcast(h2r, k);
          a0 = fmaf(hk, w0[k], a0);
          a1 = fmaf(hk, w1[k], a1);
          a2 = fmaf(hk, w2[k], a2);
        }
        float r = sigmf(gr + a0);
        float z = sigmf(gz + a1);
        float n = tanhfast(gn + r*a2);
        h2r = (1.f-z)*n + z*h2r;
      }
    } else {
      int st = i+2;
      if(st < TT){
        float v0=gib[st*192+lane], v1=gib[st*192+64+lane], v2=gib[st*192+128+lane];
        gi1b[st&3][lane]=v0; gi1b[st&3][64+lane]=v1; gi1b[st&3][128+lane]=v2;
      }
    }
    __syncthreads();
  }

  if(w == 1) h2fin[lane] = h2r;
  __syncthreads();
  if(tid < 24){
    float acc = bl[tid];
    const float4* wl4 = (const float4*)(Wl + tid*64);
    #pragma unroll
    for(int k4=0;k4<16;k4++){
      float4 h4 = *(const float4*)(h2fin + 4*k4);
      float4 w4 = wl4[k4];
      acc += h4.x*w4.x + h4.y*w4.y + h4.z*w4.z + h4.w*w4.w;
    }
    fout[b*24+tid] = acc;
  }
}

extern "C" void kernel_launch(void* const* d_in, const int* in_sizes, int n_in,
                              void* d_out, int out_size, void* d_ws, size_t ws_size,
                              hipStream_t stream){
  const float* x     =(const float*)d_in[0];
  const int*   ei    =(const int*  )d_in[1];
  const float* W1    =(const float*)d_in[3];
  const float* a_src1=(const float*)d_in[4];
  const float* a_dst1=(const float*)d_in[5];
  const float* b1    =(const float*)d_in[6];
  const float* W2    =(const float*)d_in[7];
  const float* a_src2=(const float*)d_in[8];
  const float* a_dst2=(const float*)d_in[9];
  const float* b2    =(const float*)d_in[10];
  const float* Wih0  =(const float*)d_in[11];
  const float* Whh0  =(const float*)d_in[12];
  const float* bih0  =(const float*)d_in[13];
  const float* bhh0  =(const float*)d_in[14];
  const float* Wih1  =(const float*)d_in[15];
  const float* Whh1  =(const float*)d_in[16];
  const float* bih1  =(const float*)d_in[17];
  const float* bhh1  =(const float*)d_in[18];
  const float* Wl    =(const float*)d_in[19];
  const float* bl    =(const float*)d_in[20];

  float* ws   = (float*)d_ws;
  float* h1   = ws;                  // 8388608 (dead after k_gat1)
  float* gi   = ws;                  // alias: written by k_gemm_gi after h1 is dead
  float* out1 = ws + 8388608;        // 8388608
  float* out2 = out1;                // alias (out1 dead after k_gemm2)
  float* h2   = ws + 16777216;       // 2097152
  float* as1  = ws + 18874368;       // 131072
  float* ad1  = as1 + 131072;        // 131072
  float* as2  = ad1 + 131072;        // 32768
  float* ad2  = as2 + 32768;         // 32768
  int* rowptr = (int*)(ad2 + 32768); // 32769 (padded to 32800)
  int* deg    = rowptr + 32800;      // 32768
  int* cur    = deg + 32768;         // 32768 (contiguous with deg: one memset)
  int* col    = cur + 32768;         // 557056
  float* fo   = (float*)d_out;

  hipMemsetAsync(deg, 0, 2*32768*sizeof(int), stream);  // deg + cur

  k_deg  <<<2176,256,0,stream>>>(ei,deg);
  k_scan <<<1  ,1024,0,stream>>>(deg,rowptr);
  k_fill <<<2176,256,0,stream>>>(ei,rowptr,cur,col);

  k_gemm1 <<<512 ,256,0,stream>>>(x,W1,h1);
  k_alpha1<<<512 ,256,0,stream>>>(h1,a_src1,a_dst1,as1,ad1);
  k_gat1  <<<8192,256,0,stream>>>(rowptr,col,as1,ad1,h1,b1,out1);
  k_gemm2 <<<512 ,256,0,stream>>>(out1,W2,h2);
  k_alpha2<<<128 ,256,0,stream>>>(h2,a_src2,a_dst2,as2,ad2);
  k_gat2  <<<8192,256,0,stream>>>(rowptr,col,as2,ad2,h2,b2,out2);
  k_gemm_gi<<<512,256,0,stream>>>(out2,Wih0,bih0,gi);
  k_gru_pipe<<<64,256,0,stream>>>(gi,Whh0,bhh0,Wih1,bih1,Whh1,bhh1,Wl,bl,fo);
  (void)in_sizes; (void)n_in; (void)out_size; (void)ws_size;
}